// Round 4
// baseline (1668.653 us; speedup 1.0000x reference)
//
#include <hip/hip_runtime.h>
#include <hip/hip_bf16.h>

#define NLVL 20
#define PN   5000
#define EPLE 40000
#define FDIM 128
#define HDIM 256
#define NTOT (NLVL * PN)
#define CAP  32

typedef __attribute__((ext_vector_type(8))) short short8;   // 8 bf16 in 4 VGPRs
typedef __attribute__((ext_vector_type(4))) float f32x4;

__device__ __forceinline__ f32x4 mfma16(short8 a, short8 b, f32x4 c) {
  return __builtin_amdgcn_mfma_f32_16x16x32_bf16(a, b, c, 0, 0, 0);
}

__device__ __forceinline__ ushort f2b(float f) {
  union { float f; unsigned u; } v; v.f = f;
  unsigned r = v.u + 0x7FFFu + ((v.u >> 16) & 1u);   // RNE
  return (ushort)(r >> 16);
}

__device__ __forceinline__ uint2 packu2(f32x4 v) {
  union { uint2 u2; ushort s[4]; } p;
  p.s[0] = f2b(v[0]); p.s[1] = f2b(v[1]); p.s[2] = f2b(v[2]); p.s[3] = f2b(v[3]);
  return p.u2;
}

__device__ __forceinline__ f32x4 relu4(f32x4 a) {
  f32x4 o;
  o[0] = fmaxf(a[0], 0.f); o[1] = fmaxf(a[1], 0.f);
  o[2] = fmaxf(a[2], 0.f); o[3] = fmaxf(a[3], 0.f);
  return o;
}

// ---- LDS act buffers: [16 rows][256 cols] bf16, XOR-swizzled ----
__device__ __forceinline__ void st_lds8(ushort* buf, int r, int byteoff, uint2 v) {
  *(uint2*)((char*)buf + r * 512 + (byteoff ^ ((r & 7) << 4))) = v;
}
__device__ __forceinline__ short8 ld_lds16(const ushort* buf, int r, int byteoff) {
  return *(const short8*)((const char*)buf + r * 512 + (byteoff ^ ((r & 7) << 4)));
}
__device__ __forceinline__ void rdB(const ushort* buf, short8* B, int r, int g) {
  #pragma unroll
  for (int kc = 0; kc < 8; ++kc) B[kc] = ld_lds16(buf, r, 64 * kc + 16 * g);
}
__device__ __forceinline__ void wr2(ushort* buf, f32x4 a, f32x4 b, int cc0, int r, int g) {
  st_lds8(buf, r, 32 * cc0 + 8 * g, packu2(a));
  st_lds8(buf, r, 32 * (cc0 + 1) + 8 * g, packu2(b));
}
__device__ __forceinline__ void wr2add(ushort* buf, const f32x4* X, const f32x4* Y,
                                       int cc0, int r, int g) {
  st_lds8(buf, r, 32 * cc0 + 8 * g, packu2(X[0] + Y[0]));
  st_lds8(buf, r, 32 * (cc0 + 1) + 8 * g, packu2(X[1] + Y[1]));
}

// accumulate 2 col-tiles: a[t] += Wt[16(cc0+t)+r, kc0*32 ...] @ B
__device__ __forceinline__ void accW(const ushort* __restrict__ Wt, int sK, int kc0, int nk,
                                     const short8* B, f32x4* a, int cc0, int r, int g) {
  #pragma unroll
  for (int t = 0; t < 2; ++t) {
    const ushort* wp = Wt + (size_t)(16 * (cc0 + t) + r) * sK + kc0 * 32 + 8 * g;
    #pragma unroll
    for (int kc = 0; kc < nk; ++kc)
      a[t] = mfma16(*(const short8*)(wp + kc * 32), B[kc], a[t]);
  }
}

__device__ __forceinline__ void initb(const float* bias_s, int st, f32x4* a, int cc0, int g) {
  a[0] = *(const f32x4*)(bias_s + st * 256 + 16 * cc0 + 4 * g);
  a[1] = *(const f32x4*)(bias_s + st * 256 + 16 * (cc0 + 1) + 4 * g);
}

// ---------------- CSR-lite build ----------------
__global__ void fill_csr_kernel(const int* __restrict__ esrc, const int* __restrict__ edst,
                                int* __restrict__ counts, int* __restrict__ buckets) {
  int e = blockIdx.x * 256 + threadIdx.x;
  if (e >= (NLVL - 1) * EPLE) return;
  int l = e / EPLE;
  int key = l * PN + edst[e];
  int pos = atomicAdd(&counts[key], 1);
  if (pos < CAP) buckets[(size_t)key * CAP + pos] = esrc[e];
}

// ---------------- weight prep: fp32 [K][N] -> bf16 [N][K] ----------------
__global__ void prep_w(const float* __restrict__ we, const float* __restrict__ mpw,
                       const float* __restrict__ nw0, const float* __restrict__ nww,
                       ushort* __restrict__ wet, ushort* __restrict__ mpt,
                       ushort* __restrict__ ne0t, ushort* __restrict__ nwt) {
  int i = blockIdx.x * 256 + threadIdx.x;
  if (i < 256 * 128) { int n = i >> 7, k = i & 127; wet[i] = f2b(we[k * 256 + n]); }
  if (i < 4 * 65536) { int mi = i >> 16, rr = i & 65535, n = rr >> 8, k = rr & 255;
                       mpt[i] = f2b(mpw[mi * 65536 + k * 256 + n]); }
  if (i < 256 * 512) { int n = i >> 9, k = i & 511; ne0t[i] = f2b(nw0[k * 256 + n]); }
  if (i < 3 * 65536) { int mi = i >> 16, rr = i & 65535, n = rr >> 8, k = rr & 255;
                       nwt[i] = f2b(nww[mi * 65536 + k * 256 + n]); }
}

// -------- standalone embed for level-0 rows only (final outputs) --------
__global__ __launch_bounds__(256, 4) void embed0(
    const float* __restrict__ nf, const ushort* __restrict__ wet,
    const float* __restrict__ be, float* __restrict__ out) {
  const int w = threadIdx.x >> 6, lane = threadIdx.x & 63;
  const int r = lane & 15, g = lane >> 4;
  const int rowa = blockIdx.x * 128 + w * 32 + r;
  const int rowb = rowa + 16;
  const int ra = rowa < PN ? rowa : 0;
  const int rb = rowb < PN ? rowb : 0;

  short8 Ba[4], Bb[4];
  #pragma unroll
  for (int kc = 0; kc < 4; ++kc) {
    float t[8];
    f32x4 a0 = *(const f32x4*)(nf + (size_t)ra * FDIM + kc * 32 + 8 * g);
    f32x4 a1 = *(const f32x4*)(nf + (size_t)ra * FDIM + kc * 32 + 8 * g + 4);
    t[0]=a0[0]; t[1]=a0[1]; t[2]=a0[2]; t[3]=a0[3];
    t[4]=a1[0]; t[5]=a1[1]; t[6]=a1[2]; t[7]=a1[3];
    short8 o;
    #pragma unroll
    for (int i = 0; i < 8; ++i) o[i] = (short)f2b(t[i]);
    Ba[kc] = o;
    f32x4 b0 = *(const f32x4*)(nf + (size_t)rb * FDIM + kc * 32 + 8 * g);
    f32x4 b1 = *(const f32x4*)(nf + (size_t)rb * FDIM + kc * 32 + 8 * g + 4);
    t[0]=b0[0]; t[1]=b0[1]; t[2]=b0[2]; t[3]=b0[3];
    t[4]=b1[0]; t[5]=b1[1]; t[6]=b1[2]; t[7]=b1[3];
    #pragma unroll
    for (int i = 0; i < 8; ++i) o[i] = (short)f2b(t[i]);
    Bb[kc] = o;
  }
  #pragma unroll
  for (int cc = 0; cc < 16; ++cc) {
    f32x4 bias = *(const f32x4*)(be + 16 * cc + 4 * g);
    f32x4 aa = bias, ab = bias;
    #pragma unroll
    for (int kc = 0; kc < 4; ++kc) {
      short8 wv = *(const short8*)(wet + (size_t)(16 * cc + r) * FDIM + kc * 32 + 8 * g);
      aa = mfma16(wv, Ba[kc], aa);
      ab = mfma16(wv, Bb[kc], ab);
    }
    if (rowa < PN) {
      f32x4 o; o[0]=tanhf(aa[0]); o[1]=tanhf(aa[1]); o[2]=tanhf(aa[2]); o[3]=tanhf(aa[3]);
      *(f32x4*)(out + (size_t)rowa * HDIM + 16 * cc + 4 * g) = o;
    }
    if (rowb < PN) {
      f32x4 o; o[0]=tanhf(ab[0]); o[1]=tanhf(ab[1]); o[2]=tanhf(ab[2]); o[3]=tanhf(ab[3]);
      *(f32x4*)(out + (size_t)rowb * HDIM + 16 * cc + 4 * g) = o;
    }
  }
}

// ------- fused per-level chain: 16 rows/block, 8 waves split 256 cols -------
// stages: [phase0: gather->Bs0, embed->Bs3] t0 u1 u2 mr | x0(concat) v1 v2 out
__global__ __launch_bounds__(512, 2) void level_mfma(
    float* __restrict__ eb, const float* __restrict__ nf,
    const int* __restrict__ counts, const int* __restrict__ buckets,
    const ushort* __restrict__ wet,
    const ushort* __restrict__ mpt, const ushort* __restrict__ ne0t,
    const ushort* __restrict__ nwt,
    const float* __restrict__ be, const float* __restrict__ mpb,
    const float* __restrict__ neb0, const float* __restrict__ neb, int l) {
  __shared__ ushort Bs[4][16 * 256];
  __shared__ float bias_s[9 * 256];
  __shared__ int cnt_s[16];
  const int tid = threadIdx.x, w = tid >> 6, lane = tid & 63;
  const int r = lane & 15, g = lane >> 4;
  const int p0 = blockIdx.x * 16;
  const int cc0 = 2 * w;

  // bias table -> LDS (slot: 0=be, 1..4=mp_b, 5=ne_b0, 6..8=ne_b)
  for (int i = tid; i < 2304; i += 512) {
    float v;
    if (i < 256) v = be[i];
    else if (i < 1280) v = mpb[i - 256];
    else if (i < 1536) v = neb0[i - 1280];
    else v = neb[i - 1536];
    bias_s[i] = v;
  }
  if (tid < 16) {
    int p = p0 + tid;
    cnt_s[tid] = (p < PN) ? min(counts[l * PN + p], CAP) : 0;
  }
  __syncthreads();

  // ---- phase 0: gather (wave sums 2 rows) -> Bs0 ; fused embed -> Bs3 ----
  {
    const int r0 = 2 * w, r1 = r0 + 1;
    const int c0 = cnt_s[r0], c1 = cnt_s[r1];
    const int* bk0 = buckets + (size_t)(l * PN + (p0 + r0 < PN ? p0 + r0 : 0)) * CAP;
    const int* bk1 = buckets + (size_t)(l * PN + (p0 + r1 < PN ? p0 + r1 : 0)) * CAP;
    f32x4 s0 = {0,0,0,0}, s1 = {0,0,0,0};
    int mx = c0 > c1 ? c0 : c1;
    for (int j = 0; j < mx; ++j) {
      if (j < c0) s0 += *(const f32x4*)(eb + (size_t)bk0[j] * HDIM + 4 * lane);
      if (j < c1) s1 += *(const f32x4*)(eb + (size_t)bk1[j] * HDIM + 4 * lane);
    }
    st_lds8(Bs[0], r0, 8 * lane, packu2(s0));
    st_lds8(Bs[0], r1, 8 * lane, packu2(s1));
  }
  {
    // embed: base = tanh(nf_row @ We + be) for row (l+1)*PN + p0 + r
    const float* nfr = nf + (size_t)((l + 1) * PN + (p0 + r < PN ? p0 + r : 0)) * FDIM;
    short8 Bn[4];
    #pragma unroll
    for (int kc = 0; kc < 4; ++kc) {
      f32x4 a0 = *(const f32x4*)(nfr + kc * 32 + 8 * g);
      f32x4 a1 = *(const f32x4*)(nfr + kc * 32 + 8 * g + 4);
      float t[8];
      t[0]=a0[0]; t[1]=a0[1]; t[2]=a0[2]; t[3]=a0[3];
      t[4]=a1[0]; t[5]=a1[1]; t[6]=a1[2]; t[7]=a1[3];
      short8 o;
      #pragma unroll
      for (int i = 0; i < 8; ++i) o[i] = (short)f2b(t[i]);
      Bn[kc] = o;
    }
    f32x4 a[2];
    initb(bias_s, 0, a, cc0, g);
    accW(wet, FDIM, 0, 4, Bn, a, cc0, r, g);
    f32x4 t0, t1;
    t0[0]=tanhf(a[0][0]); t0[1]=tanhf(a[0][1]); t0[2]=tanhf(a[0][2]); t0[3]=tanhf(a[0][3]);
    t1[0]=tanhf(a[1][0]); t1[1]=tanhf(a[1][1]); t1[2]=tanhf(a[1][2]); t1[3]=tanhf(a[1][3]);
    wr2(Bs[3], t0, t1, cc0, r, g);
  }
  __syncthreads();

  short8 B[8];
  f32x4 X[2], Y[2], Z[2], a[2];

  // S1: t0
  rdB(Bs[0], B, r, g);
  initb(bias_s, 1, a, cc0, g);
  accW(mpt, 256, 0, 8, B, a, cc0, r, g);
  X[0] = relu4(a[0]); X[1] = relu4(a[1]);
  wr2(Bs[1], X[0], X[1], cc0, r, g);
  __syncthreads();

  // S2: u1
  rdB(Bs[1], B, r, g);
  initb(bias_s, 2, a, cc0, g);
  accW(mpt + 65536, 256, 0, 8, B, a, cc0, r, g);
  Y[0] = relu4(a[0]); Y[1] = relu4(a[1]);
  wr2add(Bs[2], X, Y, cc0, r, g);                       // t0+u1
  __syncthreads();

  // S3: u2
  rdB(Bs[2], B, r, g);
  initb(bias_s, 3, a, cc0, g);
  accW(mpt + 131072, 256, 0, 8, B, a, cc0, r, g);
  Z[0] = relu4(a[0]); Z[1] = relu4(a[1]);
  wr2add(Bs[0], Y, Z, cc0, r, g);                       // u1+u2
  __syncthreads();

  // S4: mr
  rdB(Bs[0], B, r, g);
  initb(bias_s, 4, a, cc0, g);
  accW(mpt + 196608, 256, 0, 8, B, a, cc0, r, g);
  X[0] = relu4(a[0]); X[1] = relu4(a[1]);
  wr2(Bs[1], X[0], X[1], cc0, r, g);                    // mr
  __syncthreads();

  // S5: x0 = relu([base | mr] @ ne_w0 + b), two-pass K accumulation
  {
    short8 Bb_[8];
    rdB(Bs[3], Bb_, r, g);                              // base
    rdB(Bs[1], B, r, g);                                // mr
    initb(bias_s, 5, a, cc0, g);
    accW(ne0t, 512, 0, 8, Bb_, a, cc0, r, g);           // k 0..255
    accW(ne0t, 512, 8, 8, B,   a, cc0, r, g);           // k 256..511
  }
  Y[0] = relu4(a[0]); Y[1] = relu4(a[1]);
  wr2(Bs[0], Y[0], Y[1], cc0, r, g);                    // x0
  __syncthreads();

  // S6: v1
  rdB(Bs[0], B, r, g);
  initb(bias_s, 6, a, cc0, g);
  accW(nwt, 256, 0, 8, B, a, cc0, r, g);
  Z[0] = relu4(a[0]); Z[1] = relu4(a[1]);
  wr2add(Bs[2], Y, Z, cc0, r, g);                       // x0+v1
  __syncthreads();

  // S7: v2
  rdB(Bs[2], B, r, g);
  initb(bias_s, 7, a, cc0, g);
  accW(nwt + 65536, 256, 0, 8, B, a, cc0, r, g);
  X[0] = relu4(a[0]); X[1] = relu4(a[1]);
  wr2add(Bs[1], Z, X, cc0, r, g);                       // v1+v2
  __syncthreads();

  // S8: out
  rdB(Bs[1], B, r, g);
  initb(bias_s, 8, a, cc0, g);
  accW(nwt + 131072, 256, 0, 8, B, a, cc0, r, g);
  if (p0 + r < PN) {
    float* og = eb + ((size_t)((l + 1) * PN) + p0 + r) * HDIM;
    *(f32x4*)(og + 16 * cc0 + 4 * g)       = relu4(a[0]);
    *(f32x4*)(og + 16 * (cc0 + 1) + 4 * g) = relu4(a[1]);
  }
}

// ---------------- launch ----------------
extern "C" void kernel_launch(void* const* d_in, const int* in_sizes, int n_in,
                              void* d_out, int out_size, void* d_ws, size_t ws_size,
                              hipStream_t stream) {
  (void)in_sizes; (void)n_in; (void)out_size; (void)ws_size;
  const float* nf      = (const float*)d_in[0];
  const float* W_embed = (const float*)d_in[1];
  const float* b_embed = (const float*)d_in[2];
  const float* mp_w    = (const float*)d_in[3];
  const float* mp_b    = (const float*)d_in[4];
  const float* ne_w0   = (const float*)d_in[5];
  const float* ne_b0   = (const float*)d_in[6];
  const float* ne_w    = (const float*)d_in[7];
  const float* ne_b    = (const float*)d_in[8];
  const int*   esrc    = (const int*)d_in[9];
  const int*   edst    = (const int*)d_in[10];
  float* out = (float*)d_out;

  int*    counts  = (int*)d_ws;                                 // 95000 ints
  int*    buckets = (int*)((char*)d_ws + (512 << 10));          // 95000*32 ints (~12.2MB)
  ushort* wet     = (ushort*)((char*)d_ws + (13u << 20));       // bf16 weights, transposed
  ushort* mpt     = wet + 256 * 128;
  ushort* ne0t    = mpt + 4 * 65536;
  ushort* nwt     = ne0t + 256 * 512;

  hipMemsetAsync(counts, 0, (NLVL - 1) * PN * sizeof(int), stream);
  fill_csr_kernel<<<((NLVL - 1) * EPLE + 255) / 256, 256, 0, stream>>>(esrc, edst, counts, buckets);
  prep_w<<<1024, 256, 0, stream>>>(W_embed, mp_w, ne_w0, ne_w, wet, mpt, ne0t, nwt);
  embed0<<<(PN + 127) / 128, 256, 0, stream>>>(nf, wet, b_embed, out);
  for (int l = 0; l < NLVL - 1; ++l) {
    level_mfma<<<(PN + 15) / 16, 512, 0, stream>>>(out, nf, counts, buckets,
                                                   wet, mpt, ne0t, nwt,
                                                   b_embed, mp_b, ne_b0, ne_b, l);
  }
}